// Round 1
// baseline (820.364 us; speedup 1.0000x reference)
//
#include <hip/hip_runtime.h>
#include <hip/hip_bf16.h>
#include <stdint.h>
#include <stddef.h>

// ---------------------------------------------------------------------------
// Linear2MPO: y = x @ M + bias, M = TT-contraction of 5 cores -> [768, 3072]
// Plan:
//   1) tt_gemm x4: contract cores in fp32 (scatter epilogue reproduces the
//      einsum reshapes); final step stores Mt = M^T in bf16 [3072][768].
//   2) cast x fp32 -> bf16.
//   3) mpo_gemm: bf16 MFMA 16x16x32, 128x128 tile, BK=64, global_load_lds
//      width-16 staging with XOR k-segment swizzle, fp32 out + bias.
// ---------------------------------------------------------------------------

typedef __attribute__((ext_vector_type(8))) short short8;
typedef __attribute__((ext_vector_type(4))) float floatx4;

#define DEVINL __device__ __forceinline__

DEVINL void gload_lds16(const void* g, void* l) {
  __builtin_amdgcn_global_load_lds(
      (const __attribute__((address_space(1))) unsigned int*)g,
      (__attribute__((address_space(3))) unsigned int*)l, 16, 0, 0);
}

DEVINL unsigned short f2bf(float f) {
  unsigned int u = __float_as_uint(f);
  u = u + 0x7fffu + ((u >> 16) & 1u);  // RNE
  return (unsigned short)(u >> 16);
}

// ---------------- x fp32 -> bf16 (vectorized x4) ----------------
__global__ __launch_bounds__(256) void cast_x_kernel(
    const float4* __restrict__ x4, ushort4* __restrict__ xb4, int n4) {
  int i = blockIdx.x * blockDim.x + threadIdx.x;
  if (i >= n4) return;
  float4 v = x4[i];
  ushort4 o;
  o.x = f2bf(v.x); o.y = f2bf(v.y); o.z = f2bf(v.z); o.w = f2bf(v.w);
  xb4[i] = o;
}

// ---------------- TT contraction step as GEMM + scatter ----------------
// A: [M,K] = t flat [(I,O),r] ; B: [K,N] = core flat [r,(i,o,q)]
// C[(I,i,O,o,q)] = sum_r A*B.  If final: store Mt[out][in] bf16 (dst = in*3072+out).
__global__ __launch_bounds__(256) void tt_gemm(
    const float* __restrict__ A, const float* __restrict__ B,
    float* __restrict__ C, unsigned short* __restrict__ Ct,
    int M, int K, int N, int Odim, int idim, int odim, int qdim,
    int final_bf16_transpose) {
  __shared__ float sA[64][17];
  __shared__ float sB[16][68];
  const int tid = threadIdx.x;
  const int tx = tid & 15, ty = tid >> 4;
  const int bm = blockIdx.y, bn = blockIdx.x;
  float acc[4][4] = {};
  const int arow = tid >> 2;          // 0..63
  const int acol = (tid & 3) * 4;     // 0,4,8,12
  const int brow = tid >> 4;          // 0..15
  const int bcol = (tid & 15) * 4;    // 0..60

  for (int k0 = 0; k0 < K; k0 += 16) {
    {
      int r = bm * 64 + arow;
#pragma unroll
      for (int j = 0; j < 4; j++) {
        int k = k0 + acol + j;
        sA[arow][acol + j] = (r < M && k < K) ? A[(size_t)r * K + k] : 0.f;
      }
      int kb = k0 + brow;
#pragma unroll
      for (int j = 0; j < 4; j++) {
        int c = bn * 64 + bcol + j;
        sB[brow][bcol + j] = (kb < K && c < N) ? B[(size_t)kb * N + c] : 0.f;
      }
    }
    __syncthreads();
#pragma unroll 4
    for (int kb = 0; kb < 16; kb++) {
      float ra[4], rb[4];
#pragma unroll
      for (int r = 0; r < 4; r++) ra[r] = sA[ty * 4 + r][kb];
#pragma unroll
      for (int c = 0; c < 4; c++) rb[c] = sB[kb][tx * 4 + c];
#pragma unroll
      for (int r = 0; r < 4; r++)
#pragma unroll
        for (int c = 0; c < 4; c++) acc[r][c] += ra[r] * rb[c];
    }
    __syncthreads();
  }

  const int oq = odim * qdim;
#pragma unroll
  for (int r = 0; r < 4; r++) {
    int row = bm * 64 + ty * 4 + r;
    if (row >= M) continue;
    int I = row / Odim, O = row - I * Odim;
#pragma unroll
    for (int c = 0; c < 4; c++) {
      int col = bn * 64 + tx * 4 + c;
      if (col >= N) continue;
      int i = col / oq; int rem = col - i * oq;
      int o = rem / qdim; int q = rem - o * qdim;
      size_t dst = ((((size_t)I * idim + i) * Odim + O) * (size_t)odim + o) * qdim + q;
      if (final_bf16_transpose) {
        size_t in_ = dst / 3072, out_ = dst - in_ * 3072;
        Ct[out_ * 768 + in_] = f2bf(acc[r][c]);
      } else {
        C[dst] = acc[r][c];
      }
    }
  }
}

// ---------------- main GEMM: out[32768,3072] = Xb @ Mt^T + bias ----------------
// Xb [32768,768] bf16 row-major; Mt [3072,768] bf16 row-major (K-contiguous).
// Block: 256 thr = 4 waves, tile 128x128, BK=64.
// LDS layout [row][kseg], kseg XOR-swizzled by (row&7); identity lane->LDS
// mapping preserved for global_load_lds (swizzle applied to global src addr).
__global__ __launch_bounds__(256) void mpo_gemm(
    const unsigned short* __restrict__ Xb,
    const unsigned short* __restrict__ Mt,
    const float* __restrict__ bias,
    float* __restrict__ out) {
  __shared__ __align__(16) unsigned short sA[128 * 64];
  __shared__ __align__(16) unsigned short sB[128 * 64];
  const int tid = threadIdx.x;
  const int lane = tid & 63;
  const int wave = tid >> 6;       // 0..3
  const int bm = blockIdx.y, bn = blockIdx.x;

  // staging role: waves 0,1 -> A halves 0,1 ; waves 2,3 -> B halves 0,1
  const int is_b = wave >> 1;
  const int half = wave & 1;
  const unsigned short* gbase = is_b ? Mt : Xb;
  unsigned short* lds_base = is_b ? sB : sA;
  const int tile_row0 = (is_b ? bn : bm) * 128 + half * 64;
  const int lrow = lane >> 3;                 // 0..7 within 8-row chunk
  const int segg = (lane & 7) ^ lrow;         // swizzled global k-segment
  // per-lane global element offset for chunk j at k0: (tile_row0+j*8+lrow)*768 + k0 + segg*8
  const unsigned short* gptr[8];
#pragma unroll
  for (int j = 0; j < 8; j++)
    gptr[j] = gbase + (size_t)(tile_row0 + j * 8 + lrow) * 768 + segg * 8;

  // compute role: wave (wm,wn) owns 64x64 quadrant
  const int wm = wave & 1, wn = wave >> 1;
  const int row15 = lane & 15;
  const int kg = lane >> 4;                   // 0..3

  floatx4 acc[4][4];
#pragma unroll
  for (int mi = 0; mi < 4; mi++)
#pragma unroll
    for (int ni = 0; ni < 4; ni++) acc[mi][ni] = (floatx4){0.f, 0.f, 0.f, 0.f};

  for (int k0 = 0; k0 < 768; k0 += 64) {
    __syncthreads();  // previous compute done before LDS overwrite
#pragma unroll
    for (int j = 0; j < 8; j++) {
      unsigned short* l = lds_base + (half * 64 + j * 8) * 64;  // wave-uniform
      gload_lds16(gptr[j] + k0, l);
    }
    __syncthreads();  // staged data visible

#pragma unroll
    for (int kk = 0; kk < 2; kk++) {
      short8 af[4], bfv[4];
#pragma unroll
      for (int mi = 0; mi < 4; mi++) {
        int row = wm * 64 + mi * 16 + row15;
        int sp = (kk * 4 + kg) ^ (row & 7);
        af[mi] = *(const short8*)(sA + row * 64 + sp * 8);
      }
#pragma unroll
      for (int ni = 0; ni < 4; ni++) {
        int row = wn * 64 + ni * 16 + row15;
        int sp = (kk * 4 + kg) ^ (row & 7);
        bfv[ni] = *(const short8*)(sB + row * 64 + sp * 8);
      }
#pragma unroll
      for (int mi = 0; mi < 4; mi++)
#pragma unroll
        for (int ni = 0; ni < 4; ni++)
          acc[mi][ni] = __builtin_amdgcn_mfma_f32_16x16x32_bf16(
              af[mi], bfv[ni], acc[mi][ni], 0, 0, 0);
    }
  }

  // epilogue: C/D layout col=lane&15, row=(lane>>4)*4+reg
  const int crow = (lane >> 4) * 4;
  const int ccol = lane & 15;
#pragma unroll
  for (int ni = 0; ni < 4; ni++) {
    int col = bn * 128 + wn * 64 + ni * 16 + ccol;
    float bv = bias[col];
#pragma unroll
    for (int mi = 0; mi < 4; mi++) {
      int row0 = bm * 128 + wm * 64 + mi * 16 + crow;
      floatx4 v = acc[mi][ni];
#pragma unroll
      for (int r = 0; r < 4; r++)
        out[(size_t)(row0 + r) * 3072 + col] = v[r] + bv;
    }
  }
}

// ---------------- workspace layout (bytes) ----------------
#define OFF_T2 0u                       // 147,456 B   (t2: 12*16*192 fp32)
#define OFF_T3 147456u                  // 9,437,184 B (t3: 48*128*384 fp32)
#define OFF_T4 9584640u                 // 9,437,184 B (t4: 192*768*16 fp32)
#define OFF_MT 19021824u                // 4,718,592 B (Mt: 3072*768 bf16)
#define OFF_XB 23740416u                // 50,331,648 B (xb: 32768*768 bf16)
// total: 74,072,064 B

extern "C" void kernel_launch(void* const* d_in, const int* in_sizes, int n_in,
                              void* d_out, int out_size, void* d_ws, size_t ws_size,
                              hipStream_t stream) {
  const float* x  = (const float*)d_in[0];
  const float* c0 = (const float*)d_in[1];
  const float* c1 = (const float*)d_in[2];
  const float* c2 = (const float*)d_in[3];
  const float* c3 = (const float*)d_in[4];
  const float* c4 = (const float*)d_in[5];
  const float* bias = (const float*)d_in[6];
  float* out = (float*)d_out;
  char* ws = (char*)d_ws;

  float* t2 = (float*)(ws + OFF_T2);
  float* t3 = (float*)(ws + OFF_T3);
  float* t4 = (float*)(ws + OFF_T4);
  unsigned short* Mt = (unsigned short*)(ws + OFF_MT);
  unsigned short* xb = (unsigned short*)(ws + OFF_XB);

  // 1) x -> bf16 (25,165,824 elems / 4 per thread)
  cast_x_kernel<<<dim3(24576), dim3(256), 0, stream>>>(
      (const float4*)x, (ushort4*)xb, 6291456);

  // 2) TT contraction chain (grid = (ceil(N/64), ceil(M/64)))
  // step1: [12,12]@[12,3072]   Odim=4  idim=4 odim=4 qdim=192
  tt_gemm<<<dim3(48, 1), dim3(256), 0, stream>>>(
      c0, c1, t2, nullptr, 12, 12, 3072, 4, 4, 4, 192, 0);
  // step2: [192,192]@[192,12288] Odim=16 idim=4 odim=8 qdim=384
  tt_gemm<<<dim3(192, 3), dim3(256), 0, stream>>>(
      t2, c2, t3, nullptr, 192, 192, 12288, 16, 4, 8, 384, 0);
  // step3: [6144,384]@[384,384]  Odim=128 idim=4 odim=6 qdim=16
  tt_gemm<<<dim3(6, 96), dim3(256), 0, stream>>>(
      t3, c3, t4, nullptr, 6144, 384, 384, 128, 4, 6, 16, 0);
  // step4: [147456,16]@[16,16]   Odim=768 idim=4 odim=4 qdim=1 -> Mt bf16
  tt_gemm<<<dim3(1, 2304), dim3(256), 0, stream>>>(
      t4, c4, nullptr, Mt, 147456, 16, 16, 768, 4, 4, 1, 1);

  // 3) main GEMM: grid (N/128=24, M/128=256)
  mpo_gemm<<<dim3(24, 256), dim3(256), 0, stream>>>(xb, Mt, bias, out);
}